// Round 10
// baseline (3907.221 us; speedup 1.0000x reference)
//
#include <hip/hip_runtime.h>
#include <hip/hip_fp16.h>
#include <math.h>

#define BB 32
#define LAV 256
#define LCV 256
#define DV 300
#define HV 256
#define G3 768   // 3*H

typedef _Float16 f16x2 __attribute__((ext_vector_type(2)));
union F4H8 { float4 f4; f16x2 h2[4]; };
union U2H4 { uint2 u2; f16x2 h2[2]; };

// ---------- fast math helpers ----------
static __device__ __forceinline__ float rcp_(float x) { return __builtin_amdgcn_rcpf(x); }
static __device__ __forceinline__ float sigm(float x) { return rcp_(1.f + __expf(-x)); }
static __device__ __forceinline__ float tanh_(float x) { return 1.f - 2.f * rcp_(1.f + __expf(2.f * x)); }

// ---------- weight packing ----------
// c0: WT_a  [300][768] = W_ih_a^T (fp32)
// c1: WT_cx [300][768] = W_ih_c[:,:300]^T (fp32)
// c2: WhaRH half anchor reg slice [768 t][64 ii][2 e]: W_hh_a[t][2*ii+e]
// c3: WhaSH half anchor stream    [32 i2][768 j][2 s][2 e]: k2=64+2*i2+s, W_hh_a[j][2*k2+e]
// c4: WqH   half [128 k2][256 m][2 e] = Wq[2*k2+e][m]
// c5: WrzH  half [256 kk][512 j][2 e]: kh=kk>>7,k2i=kk&127,k=kh*256+2*k2i+e;
//     W[k][j] = k<256 ? W_hh_c[j][k] : W_ih_c[j][300+(k-256)]   (only hidden half read now)
// c6: WnH   half [256 gg][256 j][2 e]: slot=gg>>6,k2i=gg&63,grp=slot>>1,kh=slot&1,
//     kl=kh*128+2*k2i+e; grp0: W_hh_c[512+j][kl], grp1: W_ih_c[512+j][300+kl]
// c7: WcxCT fp32 [256 k][768 j] = W_ih_c[j][300+k]   (B operand for P gemm)
__global__ void prep_pack(const float* __restrict__ W_ih_a, const float* __restrict__ W_ih_c,
                          const float* __restrict__ W_hh_a, const float* __restrict__ W_hh_c,
                          const float* __restrict__ Wq,
                          float* __restrict__ WT_a, float* __restrict__ WT_cx,
                          __half* __restrict__ WhaRH, __half* __restrict__ WhaSH,
                          __half* __restrict__ WqH, __half* __restrict__ WrzH,
                          __half* __restrict__ WnH, float* __restrict__ WcxCT)
{
    int i = blockIdx.x * 256 + threadIdx.x;
    switch (blockIdx.y) {
    case 0: if (i < 230400) { int k = i / 768, n = i % 768; WT_a[i] = W_ih_a[n * 300 + k]; } break;
    case 1: if (i < 230400) { int k = i / 768, n = i % 768; WT_cx[i] = W_ih_c[n * 556 + k]; } break;
    case 2: if (i < 98304) { int e = i & 1, r = i >> 1, ii = r & 63, j = r >> 6;
            WhaRH[i] = __float2half(W_hh_a[j * 256 + 2 * ii + e]); } break;
    case 3: if (i < 98304) { int e = i & 1, s = (i >> 1) & 1, r = i >> 2, j = r % 768, i2 = r / 768;
            int k = 2 * (64 + 2 * i2 + s) + e;
            WhaSH[i] = __float2half(W_hh_a[j * 256 + k]); } break;
    case 4: if (i < 65536) { int e = i & 1, r2 = i >> 1, m = r2 & 255, k2 = r2 >> 8;
            WqH[i] = __float2half(Wq[(2 * k2 + e) * 256 + m]); } break;
    case 5: if (i < 262144) { int e = i & 1, r2 = i >> 1, j = r2 & 511, kk = r2 >> 9;
            int kh = kk >> 7, k2i = kk & 127, k = kh * 256 + 2 * k2i + e;
            float v = (k < 256) ? W_hh_c[j * 256 + k] : W_ih_c[j * 556 + 300 + (k - 256)];
            WrzH[i] = __float2half(v); } break;
    case 6: if (i < 131072) { int e = i & 1, r2 = i >> 1, j = r2 & 255, gg = r2 >> 8;
            int slot = gg >> 6, k2i = gg & 63, grp = slot >> 1, kh = slot & 1;
            int kl = kh * 128 + 2 * k2i + e;
            float v = grp ? W_ih_c[(512 + j) * 556 + 300 + kl] : W_hh_c[(512 + j) * 256 + kl];
            WnH[i] = __float2half(v); } break;
    case 7: if (i < 196608) { int k = i / 768, j = i % 768;
            WcxCT[i] = W_ih_c[j * 556 + 300 + k]; } break;
    }
}

// ---------- tiled fp32 GEMM ----------
// MODE 0: Cout[m*N+n] = acc + bias[n]                       (GI precompute)
// MODE 1: TH half2[b][h][l2] = {tanh(acc@l), tanh(acc@l+1)} (keys -> T)
// MODE 2: P2 half2[m2][N]   = {acc@m, acc@m+1}              (P = AO @ WcxCT)
template <int MODE>
__global__ __launch_bounds__(256) void gemm_tile(
    const float* __restrict__ X, const int* __restrict__ gidx, int ldx,
    const float* __restrict__ Wt, int K, int Nn,
    const float* __restrict__ bias, float* __restrict__ Cout)
{
    __shared__ __align__(16) float As[32][68];
    __shared__ __align__(16) float Bs[32][68];
    __shared__ int toks[64];
    int tid = threadIdx.x;
    int m0 = blockIdx.x * 64, n0 = blockIdx.y * 64;
    if (tid < 64) {
        int m = m0 + tid;
        if (gidx) { int t = m >> 5, b = m & 31; toks[tid] = gidx[b * LAV + t]; }
        else toks[tid] = m;
    }
    __syncthreads();
    float acc[4][4] = {};
    int tx = tid & 15, ty = tid >> 4;
    for (int k0 = 0; k0 < K; k0 += 32) {
        {
            int r = tid >> 2, cc = (tid & 3) * 8;
            const float* src = X + (size_t)toks[r] * ldx + k0 + cc;
            float4 v0 = {0.f,0.f,0.f,0.f}, v1 = {0.f,0.f,0.f,0.f};
            if (k0 + cc + 3 < K) v0 = *(const float4*)src;
            if (k0 + cc + 7 < K) v1 = *(const float4*)(src + 4);
            As[cc+0][r]=v0.x; As[cc+1][r]=v0.y; As[cc+2][r]=v0.z; As[cc+3][r]=v0.w;
            As[cc+4][r]=v1.x; As[cc+5][r]=v1.y; As[cc+6][r]=v1.z; As[cc+7][r]=v1.w;
        }
        {
            int kr = tid >> 4, c4 = (tid & 15) * 4;
            #pragma unroll
            for (int p = 0; p < 2; ++p) {
                float4 v = {0.f,0.f,0.f,0.f};
                int kg = k0 + kr + p * 16;
                if (kg < K) v = *(const float4*)(Wt + (size_t)kg * Nn + n0 + c4);
                *(float4*)&Bs[kr + p * 16][c4] = v;
            }
        }
        __syncthreads();
        #pragma unroll 8
        for (int kk = 0; kk < 32; ++kk) {
            float4 a4 = *(const float4*)&As[kk][ty * 4];
            float4 b4 = *(const float4*)&Bs[kk][tx * 4];
            acc[0][0]=fmaf(a4.x,b4.x,acc[0][0]); acc[0][1]=fmaf(a4.x,b4.y,acc[0][1]);
            acc[0][2]=fmaf(a4.x,b4.z,acc[0][2]); acc[0][3]=fmaf(a4.x,b4.w,acc[0][3]);
            acc[1][0]=fmaf(a4.y,b4.x,acc[1][0]); acc[1][1]=fmaf(a4.y,b4.y,acc[1][1]);
            acc[1][2]=fmaf(a4.y,b4.z,acc[1][2]); acc[1][3]=fmaf(a4.y,b4.w,acc[1][3]);
            acc[2][0]=fmaf(a4.z,b4.x,acc[2][0]); acc[2][1]=fmaf(a4.z,b4.y,acc[2][1]);
            acc[2][2]=fmaf(a4.z,b4.z,acc[2][2]); acc[2][3]=fmaf(a4.z,b4.w,acc[2][3]);
            acc[3][0]=fmaf(a4.w,b4.x,acc[3][0]); acc[3][1]=fmaf(a4.w,b4.y,acc[3][1]);
            acc[3][2]=fmaf(a4.w,b4.z,acc[3][2]); acc[3][3]=fmaf(a4.w,b4.w,acc[3][3]);
        }
        __syncthreads();
    }
    if (MODE == 0) {
        float4 bz = *(const float4*)&bias[n0 + tx * 4];
        #pragma unroll
        for (int i = 0; i < 4; ++i) {
            int m = m0 + ty * 4 + i;
            float4 o = { acc[i][0] + bz.x, acc[i][1] + bz.y, acc[i][2] + bz.z, acc[i][3] + bz.w };
            *(float4*)&Cout[(size_t)m * Nn + n0 + tx * 4] = o;
        }
    } else if (MODE == 1) {
        int b_ = m0 >> 8;
        int l0 = (m0 & 255) + ty * 4;
        f16x2* TH = (f16x2*)Cout;
        #pragma unroll
        for (int j = 0; j < 4; ++j) {
            int h = n0 + tx * 4 + j;
            size_t base = ((size_t)(b_ * 256 + h)) * 128 + (l0 >> 1);
            f16x2 v01 = { (_Float16)tanh_(acc[0][j]), (_Float16)tanh_(acc[1][j]) };
            f16x2 v23 = { (_Float16)tanh_(acc[2][j]), (_Float16)tanh_(acc[3][j]) };
            TH[base] = v01;
            TH[base + 1] = v23;
        }
    } else {
        int l0 = m0 + ty * 4;           // global l-row
        f16x2* P2 = (f16x2*)Cout;
        #pragma unroll
        for (int j = 0; j < 4; ++j) {
            int col = n0 + tx * 4 + j;
            f16x2 v01 = { (_Float16)acc[0][j], (_Float16)acc[1][j] };
            f16x2 v23 = { (_Float16)acc[2][j], (_Float16)acc[3][j] };
            P2[(size_t)(l0 >> 1) * 768 + col] = v01;
            P2[(size_t)((l0 >> 1) + 1) * 768 + col] = v23;
        }
    }
}

// ---------- anchor GRU: one WG/batch, fp16 (reg slice + stream) — R5/R8-proven ----------
__global__ __launch_bounds__(768) void anchor_rnn(
    const float* __restrict__ GI, const int* __restrict__ lens,
    const float* __restrict__ bhh, const __half* __restrict__ WhaRH,
    const __half* __restrict__ WhaSH,
    float* __restrict__ AO, __half* __restrict__ AOH,
    float* __restrict__ hid, float* __restrict__ outp)
{
    __shared__ float gh[768];
    __shared__ __align__(16) float hs[256];
    __shared__ __align__(16) f16x2 hx2[128];
    __shared__ float bhhS[768];
    int bid = blockIdx.x, tid = threadIdx.x;
    int len = lens[bid];

    f16x2 wreg[64];
    {
        const float4* s = (const float4*)WhaRH + (size_t)tid * 16;
        #pragma unroll
        for (int u = 0; u < 16; ++u) {
            F4H8 c; c.f4 = s[u];
            wreg[4*u+0] = c.h2[0]; wreg[4*u+1] = c.h2[1];
            wreg[4*u+2] = c.h2[2]; wreg[4*u+3] = c.h2[3];
        }
    }
    if (tid < 256) hs[tid] = 0.f;
    if (tid < 128) { f16x2 z = {(_Float16)0.f, (_Float16)0.f}; hx2[tid] = z; }
    bhhS[tid] = bhh[tid];
    float sum = 0.f;
    __syncthreads();

    for (int t = 0; t < LAV; ++t) {
        { // gh[j] = W_hh_a[j,:] @ h (+ b_hh): k2 0..63 from regs + k2 64..127 streamed
            float a0=0.f,a1=0.f,a2=0.f,a3=0.f;
            const float4* xb = (const float4*)hx2;
            #pragma unroll
            for (int u = 0; u < 16; ++u) {
                F4H8 xv; xv.f4 = xb[u];
                a0 = __builtin_amdgcn_fdot2(wreg[4*u+0], xv.h2[0], a0, false);
                a1 = __builtin_amdgcn_fdot2(wreg[4*u+1], xv.h2[1], a1, false);
                a2 = __builtin_amdgcn_fdot2(wreg[4*u+2], xv.h2[2], a2, false);
                a3 = __builtin_amdgcn_fdot2(wreg[4*u+3], xv.h2[3], a3, false);
            }
            const uint2* wsp = (const uint2*)WhaSH + tid;
            float b0=0.f,b1=0.f;
            #pragma unroll
            for (int i2 = 0; i2 < 32; ++i2) {   // full 32 i2 slots (k2 64..127)
                U2H4 w; w.u2 = wsp[(size_t)i2 * 768];
                U2H4 xx; xx.u2 = *(const uint2*)&hx2[64 + 2 * i2];
                b0 = __builtin_amdgcn_fdot2(w.h2[0], xx.h2[0], b0, false);
                b1 = __builtin_amdgcn_fdot2(w.h2[1], xx.h2[1], b1, false);
            }
            gh[tid] = ((a0 + a1) + (a2 + a3)) + (b0 + b1) + bhhS[tid];
        }
        __syncthreads();
        if (tid < 256) {
            const float* gi = GI + ((size_t)t * BB + bid) * G3;
            float r = sigm(gi[tid] + gh[tid]);
            float z = sigm(gi[256 + tid] + gh[256 + tid]);
            float n = tanh_(fmaf(r, gh[512 + tid], gi[512 + tid]));
            float hk = hs[tid];
            float hn = (1.f - z) * n + z * hk;
            bool valid = (t < len);
            float hnew = valid ? hn : hk;
            hs[tid] = hnew;
            float ov = valid ? hn : 0.f;
            AO[((size_t)bid * LAV + t) * HV + tid] = ov;
            AOH[((size_t)bid * LAV + t) * HV + tid] = __float2half(ov);
            sum += ov;
            float other = __shfl_xor(hnew, 1, 64);
            if (!(tid & 1)) {
                f16x2 v = { (_Float16)hnew, (_Float16)other };
                hx2[tid >> 1] = v;
            }
        }
        __syncthreads();
    }
    if (tid < 256) {
        outp[bid * HV + tid] = sum / (float)len;
        hid[bid * HV + tid] = hs[tid];
    }
}

// ---------- candidate GRU + attention: one WG/batch; ctx-gates via precomputed P ----------
// Phases: A(q + rz-hidden + n-hidden) B(tanh q) C(scores via T) D1(max) D2(exp+sum)
// E'(gateC[j] = sum_l attn[l] * P[l][j])  H(gate reduce + h update)
__global__ __launch_bounds__(1024) void cand_rnn(
    const float* __restrict__ GI, const int* __restrict__ lens,
    const float* __restrict__ bhh, const __half* __restrict__ WrzH,
    const __half* __restrict__ WnH, const __half* __restrict__ WqH,
    const float* __restrict__ v_att, const __half* __restrict__ P2H,
    const __half* __restrict__ TH, const float* __restrict__ hid,
    float* __restrict__ outp)
{
    __shared__ __align__(16) f16x2 x2[128];        // h pairs only (ctx never materialized)
    __shared__ __align__(16) float hs[256];
    __shared__ float tqs[256];
    __shared__ float vls[256];
    __shared__ __align__(4) __half attnH[256];     // exp(s-mx) in fp16, read as f16x2 pairs
    __shared__ __align__(16) float redBig[2048];   // q(A) -> scores(C)
    __shared__ __align__(16) float redRZh[1024];   // A -> H
    __shared__ __align__(16) float redNh[1024];    // A -> H
    __shared__ __align__(16) float gateC[768];     // E' -> H
    __shared__ float bhhS[768];
    __shared__ float wred[8];

    int tid = threadIdx.x;
    int b = blockIdx.x;
    int len = lens[b];

    const f16x2* Wq2  = (const f16x2*)WqH;
    const f16x2* Wrz2 = (const f16x2*)WrzH;
    const f16x2* Wn2  = (const f16x2*)WnH;
    const f16x2* T2   = (const f16x2*)TH + (size_t)b * 256 * 128;
    const f16x2* P2b  = (const f16x2*)P2H + (size_t)b * 128 * 768;

    if (tid < 256) { hs[tid] = hid[b * HV + tid]; vls[tid] = v_att[tid]; }
    if (tid < 768) bhhS[tid] = bhh[tid];
    __syncthreads();
    if (tid < 128) {
        f16x2 v = { (_Float16)hs[2 * tid], (_Float16)hs[2 * tid + 1] };
        x2[tid] = v;
    }
    __syncthreads();

    float csum = 0.f;

    for (int t = 0; t < LCV; ++t) {
        { // A-q: q partials, 4-way k-split (1024 thr x 32 fdot2)
            int m = tid & 255, kc = tid >> 8;
            float a0 = 0.f, a1 = 0.f;
            #pragma unroll 8
            for (int i = 0; i < 32; i += 2) {
                int k2 = kc * 32 + i;
                a0 = __builtin_amdgcn_fdot2(Wq2[k2 * 256 + m], x2[k2], a0, false);
                a1 = __builtin_amdgcn_fdot2(Wq2[(k2 + 1) * 256 + m], x2[k2 + 1], a1, false);
            }
            redBig[kc * 256 + m] = a0 + a1;
        }
        { // A-rzh: rz-gate hidden part, 2-way k-split (hidden pairs kk 0..127)
            int j = tid & 511, kh2 = tid >> 9;
            float a0 = 0.f, a1 = 0.f;
            #pragma unroll 8
            for (int i = 0; i < 64; i += 2) {
                int kk = kh2 * 64 + i;
                a0 = __builtin_amdgcn_fdot2(Wrz2[(size_t)kk * 512 + j], x2[kk], a0, false);
                a1 = __builtin_amdgcn_fdot2(Wrz2[(size_t)(kk + 1) * 512 + j], x2[kk + 1], a1, false);
            }
            redRZh[tid] = a0 + a1;
        }
        { // A-nh: n-gate hidden part, 4-way k-split (hidden slots gg 0..127)
            int j = tid & 255, q4 = tid >> 8;
            float a0 = 0.f, a1 = 0.f;
            #pragma unroll 8
            for (int i = 0; i < 32; i += 2) {
                int gg = q4 * 32 + i;
                a0 = __builtin_amdgcn_fdot2(Wn2[(size_t)gg * 256 + j], x2[gg], a0, false);
                a1 = __builtin_amdgcn_fdot2(Wn2[(size_t)(gg + 1) * 256 + j], x2[gg + 1], a1, false);
            }
            redNh[tid] = a0 + a1;
        }
        __syncthreads();
        if (tid < 256) { // B: tq = tanh(q)
            float q = redBig[tid] + redBig[256 + tid] + redBig[512 + tid] + redBig[768 + tid];
            tqs[tid] = tanh_(q);
        }
        __syncthreads();
        { // C: score partials: tanh(k+q) = (T+tq)/(1+T*tq)
            int l2 = tid & 127, hg = tid >> 7;
            float s0 = 0.f, s1 = 0.f;
            #pragma unroll 8
            for (int i = 0; i < 32; ++i) {
                int h = hg * 32 + i;
                f16x2 Tv = T2[(size_t)h * 128 + l2];
                float tq = tqs[h], vv = vls[h];
                float T0 = (float)Tv.x, T1 = (float)Tv.y;
                float d0 = fmaxf(fmaf(T0, tq, 1.f), 1e-6f);
                float d1 = fmaxf(fmaf(T1, tq, 1.f), 1e-6f);
                s0 = fmaf(vv * (T0 + tq), rcp_(d0), s0);
                s1 = fmaf(vv * (T1 + tq), rcp_(d1), s1);
            }
            redBig[hg * 256 + 2 * l2] = s0;
            redBig[hg * 256 + 2 * l2 + 1] = s1;
        }
        __syncthreads();
        float sv = 0.f;
        if (tid < 256) { // D1: reduce score partials + wave max
            #pragma unroll
            for (int hg = 0; hg < 8; ++hg) sv += redBig[hg * 256 + tid];
            float m = sv;
            #pragma unroll
            for (int o = 1; o < 64; o <<= 1) m = fmaxf(m, __shfl_xor(m, o, 64));
            if ((tid & 63) == 0) wred[tid >> 6] = m;
        }
        __syncthreads();
        if (tid < 256) { // D2: exp(s - max) in fp16 + wave sum
            float mx = fmaxf(fmaxf(wred[0], wred[1]), fmaxf(wred[2], wred[3]));
            float e = __expf(sv - mx);
            attnH[tid] = __float2half(e);
            float s = e;
            #pragma unroll
            for (int o = 1; o < 64; o <<= 1) s += __shfl_xor(s, o, 64);
            if ((tid & 63) == 0) wred[4 + (tid >> 6)] = s;
        }
        __syncthreads();
        if (tid < 768) { // E': gateC[j] = sum_l attn[l] * P[l][j]  (unnormalized)
            const f16x2* at2 = (const f16x2*)attnH;
            float a0 = 0.f, a1 = 0.f;
            #pragma unroll 8
            for (int l2 = 0; l2 < 128; l2 += 2) {
                a0 = __builtin_amdgcn_fdot2(P2b[(size_t)l2 * 768 + tid], at2[l2], a0, false);
                a1 = __builtin_amdgcn_fdot2(P2b[(size_t)(l2 + 1) * 768 + tid], at2[l2 + 1], a1, false);
            }
            gateC[tid] = a0 + a1;
        }
        __syncthreads();
        if (tid < 256) { // H: gate reduce + GRU update
            const float* gi = GI + ((size_t)t * BB + b) * G3;
            float rs = rcp_(wred[4] + wred[5] + wred[6] + wred[7]);
            float rr = (redRZh[tid] + redRZh[512 + tid]) + gateC[tid] * rs;
            float zz = (redRZh[256 + tid] + redRZh[768 + tid]) + gateC[256 + tid] * rs;
            float nh = (redNh[tid] + redNh[256 + tid]) + (redNh[512 + tid] + redNh[768 + tid]);
            float nc = gateC[512 + tid] * rs;
            float r = sigm(gi[tid] + rr + bhhS[tid]);
            float z = sigm(gi[256 + tid] + zz + bhhS[256 + tid]);
            float n = tanh_(gi[512 + tid] + nc + r * (nh + bhhS[512 + tid]));
            float hk = hs[tid];
            float hn = (1.f - z) * n + z * hk;
            float hnew = (len < t) ? hk : hn;        // strict '<' per reference
            hs[tid] = hnew;
            if (t < len) csum += hnew;
            float other = __shfl_xor(hnew, 1, 64);
            if ((tid & 1) == 0) {
                f16x2 v = { (_Float16)hnew, (_Float16)other };
                x2[tid >> 1] = v;
            }
        }
        __syncthreads();
    }
    if (tid < 256) outp[8192 + b * HV + tid] = csum / (float)len;
}

extern "C" void kernel_launch(void* const* d_in, const int* in_sizes, int n_in,
                              void* d_out, int out_size, void* d_ws, size_t ws_size,
                              hipStream_t stream) {
    const int* anchor_input     = (const int*)d_in[0];
    const int* anchor_length    = (const int*)d_in[1];
    const int* candidate_input  = (const int*)d_in[2];
    const int* candidate_length = (const int*)d_in[3];
    const float* emb    = (const float*)d_in[5];
    const float* W_ih_a = (const float*)d_in[6];
    const float* W_hh_a = (const float*)d_in[7];
    const float* b_ih_a = (const float*)d_in[8];
    const float* b_hh_a = (const float*)d_in[9];
    const float* W_ih_c = (const float*)d_in[10];
    const float* W_hh_c = (const float*)d_in[11];
    const float* b_ih_c = (const float*)d_in[12];
    const float* b_hh_c = (const float*)d_in[13];
    const float* Wq     = (const float*)d_in[14];
    const float* Wk     = (const float*)d_in[15];
    const float* v_att  = (const float*)d_in[16];
    float* out = (float*)d_out;

    // workspace layout (float units), ~71.5 MB
    float* ws = (float*)d_ws;
    size_t off = 0;
    float* GI_a  = ws + off; off += (size_t)LAV * BB * G3;     // 6291456 (dead after anchor)
    float* GI_c  = ws + off; off += (size_t)LCV * BB * G3;     // 6291456
    float* AO    = ws + off; off += (size_t)BB * LAV * HV;     // 2097152
    float* hid   = ws + off; off += (size_t)BB * HV;           // 8192
    float* WT_a  = ws + off; off += 300 * 768;                 // 230400
    float* WT_cx = ws + off; off += 300 * 768;                 // 230400
    __half* TH    = (__half*)(ws + off); off += (size_t)BB * HV * LAV / 2;  // [b][h][l2] pairs
    __half* AOH   = (__half*)(ws + off); off += (size_t)BB * LAV * HV / 2;  // [b][l][h] pairs
    __half* WhaRH = (__half*)(ws + off); off += 98304 / 2;
    __half* WhaSH = (__half*)(ws + off); off += 98304 / 2;
    __half* WqH   = (__half*)(ws + off); off += 65536 / 2;
    __half* WrzH  = (__half*)(ws + off); off += 262144 / 2;
    __half* WnH   = (__half*)(ws + off); off += 131072 / 2;
    float* WcxCT  = ws + off; off += 256 * 768;                // 196608
    // P2 [4096 l2][768] half = 12.6 MB, aliased onto GI_a (dead once anchor finishes)
    __half* P2H = (__half*)GI_a;

    prep_pack<<<dim3(1024, 8), 256, 0, stream>>>(W_ih_a, W_ih_c, W_hh_a, W_hh_c, Wq,
                                                 WT_a, WT_cx, WhaRH, WhaSH, WqH, WrzH, WnH, WcxCT);
    gemm_tile<0><<<dim3(128, 12), 256, 0, stream>>>(emb, anchor_input, DV, WT_a, DV, G3, b_ih_a, GI_a);
    gemm_tile<0><<<dim3(128, 12), 256, 0, stream>>>(emb, candidate_input, DV, WT_cx, DV, G3, b_ih_c, GI_c);
    anchor_rnn<<<32, 768, 0, stream>>>(GI_a, anchor_length, b_hh_a, WhaRH, WhaSH, AO, AOH, hid, out);
    gemm_tile<1><<<dim3(128, 4), 256, 0, stream>>>(AO, nullptr, HV, Wk, HV, HV, nullptr, (float*)TH);
    // P = AO @ W_ih_c[:,300:]^T  -> half2 pairs [l2][768]  (writes over dead GI_a)
    gemm_tile<2><<<dim3(128, 12), 256, 0, stream>>>(AO, nullptr, HV, WcxCT, HV, G3, nullptr, (float*)P2H);
    cand_rnn<<<32, 1024, 0, stream>>>(GI_c, candidate_length, b_hh_c, WrzH, WnH, WqH,
                                      v_att, P2H, TH, hid, out);
}

// Round 11
// 3786.183 us; speedup vs baseline: 1.0320x; 1.0320x over previous
//
#include <hip/hip_runtime.h>
#include <hip/hip_fp16.h>
#include <math.h>

#define BB 32
#define LAV 256
#define LCV 256
#define DV 300
#define HV 256
#define G3 768   // 3*H

typedef _Float16 f16x2 __attribute__((ext_vector_type(2)));
union F4H8 { float4 f4; f16x2 h2[4]; };
union U2H4 { uint2 u2; f16x2 h2[2]; };

// ---------- fast math helpers ----------
static __device__ __forceinline__ float rcp_(float x) { return __builtin_amdgcn_rcpf(x); }
static __device__ __forceinline__ float sigm(float x) { return rcp_(1.f + __expf(-x)); }
static __device__ __forceinline__ float tanh_(float x) { return 1.f - 2.f * rcp_(1.f + __expf(2.f * x)); }

// ---------- weight packing ----------
// c0: WT_a  [300][768] = W_ih_a^T (fp32)
// c1: WT_cx [300][768] = W_ih_c[:,:300]^T (fp32)
// c2: WhaRH half anchor reg slice [768 t][64 ii][2 e]: W_hh_a[t][2*ii+e]
// c3: WhaSH half anchor stream    [32 i2][768 j][2 s][2 e]: k2=64+2*i2+s, W_hh_a[j][2*k2+e]
// c4: WqH   half [128 k2][256 m][2 e] = Wq[2*k2+e][m]
// c5: WrzH  half [256 kk][512 j][2 e]: kh=kk>>7,k2i=kk&127,k=kh*256+2*k2i+e;
//     W[k][j] = k<256 ? W_hh_c[j][k] : W_ih_c[j][300+(k-256)]   (only hidden half read now)
// c6: WnH   half [256 gg][256 j][2 e]: slot=gg>>6,k2i=gg&63,grp=slot>>1,kh=slot&1,
//     kl=kh*128+2*k2i+e; grp0: W_hh_c[512+j][kl], grp1: W_ih_c[512+j][300+kl]
// c7: WcxCT fp32 [256 k][768 j] = W_ih_c[j][300+k]   (B operand for P gemm)
__global__ void prep_pack(const float* __restrict__ W_ih_a, const float* __restrict__ W_ih_c,
                          const float* __restrict__ W_hh_a, const float* __restrict__ W_hh_c,
                          const float* __restrict__ Wq,
                          float* __restrict__ WT_a, float* __restrict__ WT_cx,
                          __half* __restrict__ WhaRH, __half* __restrict__ WhaSH,
                          __half* __restrict__ WqH, __half* __restrict__ WrzH,
                          __half* __restrict__ WnH, float* __restrict__ WcxCT)
{
    int i = blockIdx.x * 256 + threadIdx.x;
    switch (blockIdx.y) {
    case 0: if (i < 230400) { int k = i / 768, n = i % 768; WT_a[i] = W_ih_a[n * 300 + k]; } break;
    case 1: if (i < 230400) { int k = i / 768, n = i % 768; WT_cx[i] = W_ih_c[n * 556 + k]; } break;
    case 2: if (i < 98304) { int e = i & 1, r = i >> 1, ii = r & 63, j = r >> 6;
            WhaRH[i] = __float2half(W_hh_a[j * 256 + 2 * ii + e]); } break;
    case 3: if (i < 98304) { int e = i & 1, s = (i >> 1) & 1, r = i >> 2, j = r % 768, i2 = r / 768;
            int k = 2 * (64 + 2 * i2 + s) + e;
            WhaSH[i] = __float2half(W_hh_a[j * 256 + k]); } break;
    case 4: if (i < 65536) { int e = i & 1, r2 = i >> 1, m = r2 & 255, k2 = r2 >> 8;
            WqH[i] = __float2half(Wq[(2 * k2 + e) * 256 + m]); } break;
    case 5: if (i < 262144) { int e = i & 1, r2 = i >> 1, j = r2 & 511, kk = r2 >> 9;
            int kh = kk >> 7, k2i = kk & 127, k = kh * 256 + 2 * k2i + e;
            float v = (k < 256) ? W_hh_c[j * 256 + k] : W_ih_c[j * 556 + 300 + (k - 256)];
            WrzH[i] = __float2half(v); } break;
    case 6: if (i < 131072) { int e = i & 1, r2 = i >> 1, j = r2 & 255, gg = r2 >> 8;
            int slot = gg >> 6, k2i = gg & 63, grp = slot >> 1, kh = slot & 1;
            int kl = kh * 128 + 2 * k2i + e;
            float v = grp ? W_ih_c[(512 + j) * 556 + 300 + kl] : W_hh_c[(512 + j) * 256 + kl];
            WnH[i] = __float2half(v); } break;
    case 7: if (i < 196608) { int k = i / 768, j = i % 768;
            WcxCT[i] = W_ih_c[j * 556 + 300 + k]; } break;
    }
}

// ---------- tiled fp32 GEMM ----------
// MODE 0: Cout[m*N+n] = acc + bias[n]                       (GI precompute)
// MODE 1: TH half2[b][h][l2] = {tanh(acc@l), tanh(acc@l+1)} (keys -> T)
// MODE 2: P2 half2[m2][N]   = {acc@m, acc@m+1}              (P = AO @ WcxCT)
template <int MODE>
__global__ __launch_bounds__(256) void gemm_tile(
    const float* __restrict__ X, const int* __restrict__ gidx, int ldx,
    const float* __restrict__ Wt, int K, int Nn,
    const float* __restrict__ bias, float* __restrict__ Cout)
{
    __shared__ __align__(16) float As[32][68];
    __shared__ __align__(16) float Bs[32][68];
    __shared__ int toks[64];
    int tid = threadIdx.x;
    int m0 = blockIdx.x * 64, n0 = blockIdx.y * 64;
    if (tid < 64) {
        int m = m0 + tid;
        if (gidx) { int t = m >> 5, b = m & 31; toks[tid] = gidx[b * LAV + t]; }
        else toks[tid] = m;
    }
    __syncthreads();
    float acc[4][4] = {};
    int tx = tid & 15, ty = tid >> 4;
    for (int k0 = 0; k0 < K; k0 += 32) {
        {
            int r = tid >> 2, cc = (tid & 3) * 8;
            const float* src = X + (size_t)toks[r] * ldx + k0 + cc;
            float4 v0 = {0.f,0.f,0.f,0.f}, v1 = {0.f,0.f,0.f,0.f};
            if (k0 + cc + 3 < K) v0 = *(const float4*)src;
            if (k0 + cc + 7 < K) v1 = *(const float4*)(src + 4);
            As[cc+0][r]=v0.x; As[cc+1][r]=v0.y; As[cc+2][r]=v0.z; As[cc+3][r]=v0.w;
            As[cc+4][r]=v1.x; As[cc+5][r]=v1.y; As[cc+6][r]=v1.z; As[cc+7][r]=v1.w;
        }
        {
            int kr = tid >> 4, c4 = (tid & 15) * 4;
            #pragma unroll
            for (int p = 0; p < 2; ++p) {
                float4 v = {0.f,0.f,0.f,0.f};
                int kg = k0 + kr + p * 16;
                if (kg < K) v = *(const float4*)(Wt + (size_t)kg * Nn + n0 + c4);
                *(float4*)&Bs[kr + p * 16][c4] = v;
            }
        }
        __syncthreads();
        #pragma unroll 8
        for (int kk = 0; kk < 32; ++kk) {
            float4 a4 = *(const float4*)&As[kk][ty * 4];
            float4 b4 = *(const float4*)&Bs[kk][tx * 4];
            acc[0][0]=fmaf(a4.x,b4.x,acc[0][0]); acc[0][1]=fmaf(a4.x,b4.y,acc[0][1]);
            acc[0][2]=fmaf(a4.x,b4.z,acc[0][2]); acc[0][3]=fmaf(a4.x,b4.w,acc[0][3]);
            acc[1][0]=fmaf(a4.y,b4.x,acc[1][0]); acc[1][1]=fmaf(a4.y,b4.y,acc[1][1]);
            acc[1][2]=fmaf(a4.y,b4.z,acc[1][2]); acc[1][3]=fmaf(a4.y,b4.w,acc[1][3]);
            acc[2][0]=fmaf(a4.z,b4.x,acc[2][0]); acc[2][1]=fmaf(a4.z,b4.y,acc[2][1]);
            acc[2][2]=fmaf(a4.z,b4.z,acc[2][2]); acc[2][3]=fmaf(a4.z,b4.w,acc[2][3]);
            acc[3][0]=fmaf(a4.w,b4.x,acc[3][0]); acc[3][1]=fmaf(a4.w,b4.y,acc[3][1]);
            acc[3][2]=fmaf(a4.w,b4.z,acc[3][2]); acc[3][3]=fmaf(a4.w,b4.w,acc[3][3]);
        }
        __syncthreads();
    }
    if (MODE == 0) {
        float4 bz = *(const float4*)&bias[n0 + tx * 4];
        #pragma unroll
        for (int i = 0; i < 4; ++i) {
            int m = m0 + ty * 4 + i;
            float4 o = { acc[i][0] + bz.x, acc[i][1] + bz.y, acc[i][2] + bz.z, acc[i][3] + bz.w };
            *(float4*)&Cout[(size_t)m * Nn + n0 + tx * 4] = o;
        }
    } else if (MODE == 1) {
        int b_ = m0 >> 8;
        int l0 = (m0 & 255) + ty * 4;
        f16x2* TH = (f16x2*)Cout;
        #pragma unroll
        for (int j = 0; j < 4; ++j) {
            int h = n0 + tx * 4 + j;
            size_t base = ((size_t)(b_ * 256 + h)) * 128 + (l0 >> 1);
            f16x2 v01 = { (_Float16)tanh_(acc[0][j]), (_Float16)tanh_(acc[1][j]) };
            f16x2 v23 = { (_Float16)tanh_(acc[2][j]), (_Float16)tanh_(acc[3][j]) };
            TH[base] = v01;
            TH[base + 1] = v23;
        }
    } else {
        int l0 = m0 + ty * 4;           // global l-row
        f16x2* P2 = (f16x2*)Cout;
        #pragma unroll
        for (int j = 0; j < 4; ++j) {
            int col = n0 + tx * 4 + j;
            f16x2 v01 = { (_Float16)acc[0][j], (_Float16)acc[1][j] };
            f16x2 v23 = { (_Float16)acc[2][j], (_Float16)acc[3][j] };
            P2[(size_t)(l0 >> 1) * 768 + col] = v01;
            P2[(size_t)((l0 >> 1) + 1) * 768 + col] = v23;
        }
    }
}

// ---------- anchor GRU: one WG/batch, fp16 (reg slice + stream) — R5/R8-proven ----------
__global__ __launch_bounds__(768) void anchor_rnn(
    const float* __restrict__ GI, const int* __restrict__ lens,
    const float* __restrict__ bhh, const __half* __restrict__ WhaRH,
    const __half* __restrict__ WhaSH,
    float* __restrict__ AO, __half* __restrict__ AOH,
    float* __restrict__ hid, float* __restrict__ outp)
{
    __shared__ float gh[768];
    __shared__ __align__(16) float hs[256];
    __shared__ __align__(16) f16x2 hx2[128];
    __shared__ float bhhS[768];
    int bid = blockIdx.x, tid = threadIdx.x;
    int len = lens[bid];

    f16x2 wreg[64];
    {
        const float4* s = (const float4*)WhaRH + (size_t)tid * 16;
        #pragma unroll
        for (int u = 0; u < 16; ++u) {
            F4H8 c; c.f4 = s[u];
            wreg[4*u+0] = c.h2[0]; wreg[4*u+1] = c.h2[1];
            wreg[4*u+2] = c.h2[2]; wreg[4*u+3] = c.h2[3];
        }
    }
    if (tid < 256) hs[tid] = 0.f;
    if (tid < 128) { f16x2 z = {(_Float16)0.f, (_Float16)0.f}; hx2[tid] = z; }
    bhhS[tid] = bhh[tid];
    float sum = 0.f;
    __syncthreads();

    for (int t = 0; t < LAV; ++t) {
        { // gh[j] = W_hh_a[j,:] @ h (+ b_hh): k2 0..63 from regs + k2 64..127 streamed
            float a0=0.f,a1=0.f,a2=0.f,a3=0.f;
            const float4* xb = (const float4*)hx2;
            #pragma unroll
            for (int u = 0; u < 16; ++u) {
                F4H8 xv; xv.f4 = xb[u];
                a0 = __builtin_amdgcn_fdot2(wreg[4*u+0], xv.h2[0], a0, false);
                a1 = __builtin_amdgcn_fdot2(wreg[4*u+1], xv.h2[1], a1, false);
                a2 = __builtin_amdgcn_fdot2(wreg[4*u+2], xv.h2[2], a2, false);
                a3 = __builtin_amdgcn_fdot2(wreg[4*u+3], xv.h2[3], a3, false);
            }
            const uint2* wsp = (const uint2*)WhaSH + tid;
            float b0=0.f,b1=0.f;
            #pragma unroll
            for (int i2 = 0; i2 < 32; ++i2) {   // full 32 i2 slots (k2 64..127)
                U2H4 w; w.u2 = wsp[(size_t)i2 * 768];
                U2H4 xx; xx.u2 = *(const uint2*)&hx2[64 + 2 * i2];
                b0 = __builtin_amdgcn_fdot2(w.h2[0], xx.h2[0], b0, false);
                b1 = __builtin_amdgcn_fdot2(w.h2[1], xx.h2[1], b1, false);
            }
            gh[tid] = ((a0 + a1) + (a2 + a3)) + (b0 + b1) + bhhS[tid];
        }
        __syncthreads();
        if (tid < 256) {
            const float* gi = GI + ((size_t)t * BB + bid) * G3;
            float r = sigm(gi[tid] + gh[tid]);
            float z = sigm(gi[256 + tid] + gh[256 + tid]);
            float n = tanh_(fmaf(r, gh[512 + tid], gi[512 + tid]));
            float hk = hs[tid];
            float hn = (1.f - z) * n + z * hk;
            bool valid = (t < len);
            float hnew = valid ? hn : hk;
            hs[tid] = hnew;
            float ov = valid ? hn : 0.f;
            AO[((size_t)bid * LAV + t) * HV + tid] = ov;
            AOH[((size_t)bid * LAV + t) * HV + tid] = __float2half(ov);
            sum += ov;
            float other = __shfl_xor(hnew, 1, 64);
            if (!(tid & 1)) {
                f16x2 v = { (_Float16)hnew, (_Float16)other };
                hx2[tid >> 1] = v;
            }
        }
        __syncthreads();
    }
    if (tid < 256) {
        outp[bid * HV + tid] = sum / (float)len;
        hid[bid * HV + tid] = hs[tid];
    }
}

// ---------- candidate GRU + attention: one WG/batch; full-output phase A, 6 barriers ----------
// A(q full+tanh | rzh full | nh full; GI prefetch) C(scores) D1(max) D2(exp+sum)
// E'(gateC = attn @ P) H(gate + h update)
__global__ __launch_bounds__(1024) void cand_rnn(
    const float* __restrict__ GI, const int* __restrict__ lens,
    const float* __restrict__ bhh, const __half* __restrict__ WrzH,
    const __half* __restrict__ WnH, const __half* __restrict__ WqH,
    const float* __restrict__ v_att, const __half* __restrict__ P2H,
    const __half* __restrict__ TH, const float* __restrict__ hid,
    float* __restrict__ outp)
{
    __shared__ __align__(16) f16x2 x2[128];        // h pairs
    __shared__ __align__(16) float hs[256];
    __shared__ __align__(16) float2 tqv[256];      // {tq, v*tq}
    __shared__ float vls[256];
    __shared__ __align__(4) __half attnH[256];     // exp(s-mx) fp16, read as f16x2 pairs
    __shared__ __align__(16) float redBig[2048];   // score partials (C)
    __shared__ __align__(16) float redRZh[512];    // A -> H (complete sums)
    __shared__ __align__(16) float redNh[256];     // A -> H (complete sums)
    __shared__ __align__(16) float gateC[768];     // E' -> H
    __shared__ float bhhS[768];
    __shared__ float wred[8];

    int tid = threadIdx.x;
    int b = blockIdx.x;
    int len = lens[b];

    const f16x2* Wq2  = (const f16x2*)WqH;
    const f16x2* Wrz2 = (const f16x2*)WrzH;
    const f16x2* Wn2  = (const f16x2*)WnH;
    const f16x2* T2   = (const f16x2*)TH + (size_t)b * 256 * 128;
    const f16x2* P2b  = (const f16x2*)P2H + (size_t)b * 128 * 768;

    if (tid < 256) { hs[tid] = hid[b * HV + tid]; vls[tid] = v_att[tid]; }
    if (tid < 768) bhhS[tid] = bhh[tid];
    __syncthreads();
    if (tid < 128) {
        f16x2 v = { (_Float16)hs[2 * tid], (_Float16)hs[2 * tid + 1] };
        x2[tid] = v;
    }
    __syncthreads();

    float csum = 0.f;

    for (int t = 0; t < LCV; ++t) {
        float gir = 0.f, giz = 0.f, gin = 0.f;
        // ---- A: full-output role split (one barrier total) ----
        if (tid < 256) {
            // GI prefetch (consumed in H, 4 phases later)
            const float* gi = GI + ((size_t)t * BB + b) * G3 + tid;
            gir = gi[0]; giz = gi[256]; gin = gi[512];
            // q[m] complete: 128 fdot2 + tanh
            int m = tid;
            float a0 = 0.f, a1 = 0.f, a2 = 0.f, a3 = 0.f;
            #pragma unroll 8
            for (int k2 = 0; k2 < 128; k2 += 4) {
                a0 = __builtin_amdgcn_fdot2(Wq2[(k2 + 0) * 256 + m], x2[k2 + 0], a0, false);
                a1 = __builtin_amdgcn_fdot2(Wq2[(k2 + 1) * 256 + m], x2[k2 + 1], a1, false);
                a2 = __builtin_amdgcn_fdot2(Wq2[(k2 + 2) * 256 + m], x2[k2 + 2], a2, false);
                a3 = __builtin_amdgcn_fdot2(Wq2[(k2 + 3) * 256 + m], x2[k2 + 3], a3, false);
            }
            float tq = tanh_((a0 + a1) + (a2 + a3));
            tqv[m] = make_float2(tq, vls[m] * tq);
        } else if (tid < 768) {
            // rz-hidden[j] complete: 128 fdot2
            int j = tid - 256;
            float a0 = 0.f, a1 = 0.f, a2 = 0.f, a3 = 0.f;
            #pragma unroll 8
            for (int kk = 0; kk < 128; kk += 4) {
                a0 = __builtin_amdgcn_fdot2(Wrz2[(size_t)(kk + 0) * 512 + j], x2[kk + 0], a0, false);
                a1 = __builtin_amdgcn_fdot2(Wrz2[(size_t)(kk + 1) * 512 + j], x2[kk + 1], a1, false);
                a2 = __builtin_amdgcn_fdot2(Wrz2[(size_t)(kk + 2) * 512 + j], x2[kk + 2], a2, false);
                a3 = __builtin_amdgcn_fdot2(Wrz2[(size_t)(kk + 3) * 512 + j], x2[kk + 3], a3, false);
            }
            redRZh[j] = (a0 + a1) + (a2 + a3);
        } else {
            // n-hidden[j] complete: 128 fdot2
            int j = tid - 768;
            float a0 = 0.f, a1 = 0.f, a2 = 0.f, a3 = 0.f;
            #pragma unroll 8
            for (int gg = 0; gg < 128; gg += 4) {
                a0 = __builtin_amdgcn_fdot2(Wn2[(size_t)(gg + 0) * 256 + j], x2[gg + 0], a0, false);
                a1 = __builtin_amdgcn_fdot2(Wn2[(size_t)(gg + 1) * 256 + j], x2[gg + 1], a1, false);
                a2 = __builtin_amdgcn_fdot2(Wn2[(size_t)(gg + 2) * 256 + j], x2[gg + 2], a2, false);
                a3 = __builtin_amdgcn_fdot2(Wn2[(size_t)(gg + 3) * 256 + j], x2[gg + 3], a3, false);
            }
            redNh[j] = (a0 + a1) + (a2 + a3);
        }
        __syncthreads();
        { // C: score partials: v*tanh(K+q) = (v*T + v*tq) / (1 + T*tq)
            int l2 = tid & 127, hg = tid >> 7;
            const f16x2* Tb = T2 + (size_t)(hg * 32) * 128 + l2;
            float s0 = 0.f, s1 = 0.f;
            #pragma unroll 8
            for (int i = 0; i < 32; ++i) {
                f16x2 Tv = Tb[(size_t)i * 128];
                float2 tv = tqv[hg * 32 + i];
                float vv = vls[hg * 32 + i];
                float T0 = (float)Tv.x, T1 = (float)Tv.y;
                float d0 = fmaxf(fmaf(T0, tv.x, 1.f), 1e-6f);
                float d1 = fmaxf(fmaf(T1, tv.x, 1.f), 1e-6f);
                s0 = fmaf(fmaf(vv, T0, tv.y), rcp_(d0), s0);
                s1 = fmaf(fmaf(vv, T1, tv.y), rcp_(d1), s1);
            }
            redBig[hg * 256 + 2 * l2] = s0;
            redBig[hg * 256 + 2 * l2 + 1] = s1;
        }
        __syncthreads();
        float sv = 0.f;
        if (tid < 256) { // D1: reduce score partials + wave max
            #pragma unroll
            for (int hg = 0; hg < 8; ++hg) sv += redBig[hg * 256 + tid];
            float m = sv;
            #pragma unroll
            for (int o = 1; o < 64; o <<= 1) m = fmaxf(m, __shfl_xor(m, o, 64));
            if ((tid & 63) == 0) wred[tid >> 6] = m;
        }
        __syncthreads();
        if (tid < 256) { // D2: exp(s - max) in fp16 + wave sum
            float mx = fmaxf(fmaxf(wred[0], wred[1]), fmaxf(wred[2], wred[3]));
            float e = __expf(sv - mx);
            attnH[tid] = __float2half(e);
            float s = e;
            #pragma unroll
            for (int o = 1; o < 64; o <<= 1) s += __shfl_xor(s, o, 64);
            if ((tid & 63) == 0) wred[4 + (tid >> 6)] = s;
        }
        __syncthreads();
        if (tid < 768) { // E': gateC[j] = sum_l attn[l] * P[l][j]  (unnormalized)
            const f16x2* at2 = (const f16x2*)attnH;
            float a0 = 0.f, a1 = 0.f;
            #pragma unroll 8
            for (int l2 = 0; l2 < 128; l2 += 2) {
                a0 = __builtin_amdgcn_fdot2(P2b[(size_t)l2 * 768 + tid], at2[l2], a0, false);
                a1 = __builtin_amdgcn_fdot2(P2b[(size_t)(l2 + 1) * 768 + tid], at2[l2 + 1], a1, false);
            }
            gateC[tid] = a0 + a1;
        }
        __syncthreads();
        if (tid < 256) { // H: gate + GRU update (complete sums, prefetched gi)
            float rs = rcp_(wred[4] + wred[5] + wred[6] + wred[7]);
            float rr = redRZh[tid] + gateC[tid] * rs;
            float zz = redRZh[256 + tid] + gateC[256 + tid] * rs;
            float nh = redNh[tid];
            float nc = gateC[512 + tid] * rs;
            float r = sigm(gir + rr + bhhS[tid]);
            float z = sigm(giz + zz + bhhS[256 + tid]);
            float n = tanh_(gin + nc + r * (nh + bhhS[512 + tid]));
            float hk = hs[tid];
            float hn = (1.f - z) * n + z * hk;
            float hnew = (len < t) ? hk : hn;        // strict '<' per reference
            hs[tid] = hnew;
            if (t < len) csum += hnew;
            float other = __shfl_xor(hnew, 1, 64);
            if ((tid & 1) == 0) {
                f16x2 v = { (_Float16)hnew, (_Float16)other };
                x2[tid >> 1] = v;
            }
        }
        __syncthreads();
    }
    if (tid < 256) outp[8192 + b * HV + tid] = csum / (float)len;
}

extern "C" void kernel_launch(void* const* d_in, const int* in_sizes, int n_in,
                              void* d_out, int out_size, void* d_ws, size_t ws_size,
                              hipStream_t stream) {
    const int* anchor_input     = (const int*)d_in[0];
    const int* anchor_length    = (const int*)d_in[1];
    const int* candidate_input  = (const int*)d_in[2];
    const int* candidate_length = (const int*)d_in[3];
    const float* emb    = (const float*)d_in[5];
    const float* W_ih_a = (const float*)d_in[6];
    const float* W_hh_a = (const float*)d_in[7];
    const float* b_ih_a = (const float*)d_in[8];
    const float* b_hh_a = (const float*)d_in[9];
    const float* W_ih_c = (const float*)d_in[10];
    const float* W_hh_c = (const float*)d_in[11];
    const float* b_ih_c = (const float*)d_in[12];
    const float* b_hh_c = (const float*)d_in[13];
    const float* Wq     = (const float*)d_in[14];
    const float* Wk     = (const float*)d_in[15];
    const float* v_att  = (const float*)d_in[16];
    float* out = (float*)d_out;

    // workspace layout (float units), ~71.5 MB
    float* ws = (float*)d_ws;
    size_t off = 0;
    float* GI_a  = ws + off; off += (size_t)LAV * BB * G3;     // 6291456 (dead after anchor)
    float* GI_c  = ws + off; off += (size_t)LCV * BB * G3;     // 6291456
    float* AO    = ws + off; off += (size_t)BB * LAV * HV;     // 2097152
    float* hid   = ws + off; off += (size_t)BB * HV;           // 8192
    float* WT_a  = ws + off; off += 300 * 768;                 // 230400
    float* WT_cx = ws + off; off += 300 * 768;                 // 230400
    __half* TH    = (__half*)(ws + off); off += (size_t)BB * HV * LAV / 2;  // [b][h][l2] pairs
    __half* AOH   = (__half*)(ws + off); off += (size_t)BB * LAV * HV / 2;  // [b][l][h] pairs
    __half* WhaRH = (__half*)(ws + off); off += 98304 / 2;
    __half* WhaSH = (__half*)(ws + off); off += 98304 / 2;
    __half* WqH   = (__half*)(ws + off); off += 65536 / 2;
    __half* WrzH  = (__half*)(ws + off); off += 262144 / 2;
    __half* WnH   = (__half*)(ws + off); off += 131072 / 2;
    float* WcxCT  = ws + off; off += 256 * 768;                // 196608
    // P2 [4096 l2][768] half = 12.6 MB, aliased onto GI_a (dead once anchor finishes)
    __half* P2H = (__half*)GI_a;

    prep_pack<<<dim3(1024, 8), 256, 0, stream>>>(W_ih_a, W_ih_c, W_hh_a, W_hh_c, Wq,
                                                 WT_a, WT_cx, WhaRH, WhaSH, WqH, WrzH, WnH, WcxCT);
    gemm_tile<0><<<dim3(128, 12), 256, 0, stream>>>(emb, anchor_input, DV, WT_a, DV, G3, b_ih_a, GI_a);
    gemm_tile<0><<<dim3(128, 12), 256, 0, stream>>>(emb, candidate_input, DV, WT_cx, DV, G3, b_ih_c, GI_c);
    anchor_rnn<<<32, 768, 0, stream>>>(GI_a, anchor_length, b_hh_a, WhaRH, WhaSH, AO, AOH, hid, out);
    gemm_tile<1><<<dim3(128, 4), 256, 0, stream>>>(AO, nullptr, HV, Wk, HV, HV, nullptr, (float*)TH);
    // P = AO @ W_ih_c[:,300:]^T  -> half2 pairs [l2][768]  (writes over dead GI_a)
    gemm_tile<2><<<dim3(128, 12), 256, 0, stream>>>(AO, nullptr, HV, WcxCT, HV, G3, nullptr, (float*)P2H);
    cand_rnn<<<32, 1024, 0, stream>>>(GI_c, candidate_length, b_hh_c, WrzH, WnH, WqH,
                                      v_att, P2H, TH, hid, out);
}

// Round 12
// 3554.890 us; speedup vs baseline: 1.0991x; 1.0651x over previous
//
#include <hip/hip_runtime.h>
#include <hip/hip_fp16.h>
#include <math.h>

#define BB 32
#define LAV 256
#define LCV 256
#define DV 300
#define HV 256
#define G3 768   // 3*H

typedef _Float16 f16x2 __attribute__((ext_vector_type(2)));
union F4H8 { float4 f4; f16x2 h2[4]; };
union U2H4 { uint2 u2; f16x2 h2[2]; };

// ---------- fast math helpers ----------
static __device__ __forceinline__ float rcp_(float x) { return __builtin_amdgcn_rcpf(x); }
static __device__ __forceinline__ float sigm(float x) { return rcp_(1.f + __expf(-x)); }
static __device__ __forceinline__ float tanh_(float x) { return 1.f - 2.f * rcp_(1.f + __expf(2.f * x)); }

// ---------- weight packing ----------
// c0: WT_a  [300][768] = W_ih_a^T (fp32)
// c1: WT_cx [300][768] = W_ih_c[:,:300]^T (fp32)
// c2: WhaRH half anchor reg slice [768 t][64 ii][2 e]: W_hh_a[t][2*ii+e]
// c3: WhaSH half anchor stream    [32 i2][768 j][2 s][2 e]: k2=64+2*i2+s, W_hh_a[j][2*k2+e]
// c4: Wq4   half [32 kq][256 m][4 c][2 e]  = Wq[8kq+2c+e][m]          (quad-k pack)
// c5: Wrz4  half [32 kq][512 j][4 c][2 e]  = W_hh_c[j][8kq+2c+e]      (rz hidden only)
// c6: Wn4   half [32 kq][256 j][4 c][2 e]  = W_hh_c[512+j][8kq+2c+e]  (n hidden only)
// c7: WcxCT fp32 [256 k][768 j] = W_ih_c[j][300+k]   (B operand for P gemm)
__global__ void prep_pack(const float* __restrict__ W_ih_a, const float* __restrict__ W_ih_c,
                          const float* __restrict__ W_hh_a, const float* __restrict__ W_hh_c,
                          const float* __restrict__ Wq,
                          float* __restrict__ WT_a, float* __restrict__ WT_cx,
                          __half* __restrict__ WhaRH, __half* __restrict__ WhaSH,
                          __half* __restrict__ Wq4, __half* __restrict__ Wrz4,
                          __half* __restrict__ Wn4, float* __restrict__ WcxCT)
{
    int i = blockIdx.x * 256 + threadIdx.x;
    switch (blockIdx.y) {
    case 0: if (i < 230400) { int k = i / 768, n = i % 768; WT_a[i] = W_ih_a[n * 300 + k]; } break;
    case 1: if (i < 230400) { int k = i / 768, n = i % 768; WT_cx[i] = W_ih_c[n * 556 + k]; } break;
    case 2: if (i < 98304) { int e = i & 1, r = i >> 1, ii = r & 63, j = r >> 6;
            WhaRH[i] = __float2half(W_hh_a[j * 256 + 2 * ii + e]); } break;
    case 3: if (i < 98304) { int e = i & 1, s = (i >> 1) & 1, r = i >> 2, j = r % 768, i2 = r / 768;
            int k = 2 * (64 + 2 * i2 + s) + e;
            WhaSH[i] = __float2half(W_hh_a[j * 256 + k]); } break;
    case 4: if (i < 65536) { int e = i & 1, c = (i >> 1) & 3, r = i >> 3, m = r & 255, kq = r >> 8;
            int k = 8 * kq + 2 * c + e;
            Wq4[i] = __float2half(Wq[k * 256 + m]); } break;
    case 5: if (i < 131072) { int e = i & 1, c = (i >> 1) & 3, r = i >> 3, j = r & 511, kq = r >> 9;
            int k = 8 * kq + 2 * c + e;
            Wrz4[i] = __float2half(W_hh_c[j * 256 + k]); } break;
    case 6: if (i < 65536) { int e = i & 1, c = (i >> 1) & 3, r = i >> 3, j = r & 255, kq = r >> 8;
            int k = 8 * kq + 2 * c + e;
            Wn4[i] = __float2half(W_hh_c[(512 + j) * 256 + k]); } break;
    case 7: if (i < 196608) { int k = i / 768, j = i % 768;
            WcxCT[i] = W_ih_c[j * 556 + 300 + k]; } break;
    }
}

// ---------- tiled fp32 GEMM ----------
// MODE 0: Cout[m*N+n] = acc + bias[n]                           (GI precompute)
// MODE 1: T4 half[b][hq 64][l2 128][4 c][2 e] = tanh(keys)      (h=4hq+c, l=2*l2+e)
// MODE 2: P4 half[lq 1024][768 col][4 c][2 e] = P               (l=8lq+2c+e global row)
template <int MODE>
__global__ __launch_bounds__(256) void gemm_tile(
    const float* __restrict__ X, const int* __restrict__ gidx, int ldx,
    const float* __restrict__ Wt, int K, int Nn,
    const float* __restrict__ bias, float* __restrict__ Cout)
{
    __shared__ __align__(16) float As[32][68];
    __shared__ __align__(16) float Bs[32][68];
    __shared__ int toks[64];
    int tid = threadIdx.x;
    int m0 = blockIdx.x * 64, n0 = blockIdx.y * 64;
    if (tid < 64) {
        int m = m0 + tid;
        if (gidx) { int t = m >> 5, b = m & 31; toks[tid] = gidx[b * LAV + t]; }
        else toks[tid] = m;
    }
    __syncthreads();
    float acc[4][4] = {};
    int tx = tid & 15, ty = tid >> 4;
    for (int k0 = 0; k0 < K; k0 += 32) {
        {
            int r = tid >> 2, cc = (tid & 3) * 8;
            const float* src = X + (size_t)toks[r] * ldx + k0 + cc;
            float4 v0 = {0.f,0.f,0.f,0.f}, v1 = {0.f,0.f,0.f,0.f};
            if (k0 + cc + 3 < K) v0 = *(const float4*)src;
            if (k0 + cc + 7 < K) v1 = *(const float4*)(src + 4);
            As[cc+0][r]=v0.x; As[cc+1][r]=v0.y; As[cc+2][r]=v0.z; As[cc+3][r]=v0.w;
            As[cc+4][r]=v1.x; As[cc+5][r]=v1.y; As[cc+6][r]=v1.z; As[cc+7][r]=v1.w;
        }
        {
            int kr = tid >> 4, c4 = (tid & 15) * 4;
            #pragma unroll
            for (int p = 0; p < 2; ++p) {
                float4 v = {0.f,0.f,0.f,0.f};
                int kg = k0 + kr + p * 16;
                if (kg < K) v = *(const float4*)(Wt + (size_t)kg * Nn + n0 + c4);
                *(float4*)&Bs[kr + p * 16][c4] = v;
            }
        }
        __syncthreads();
        #pragma unroll 8
        for (int kk = 0; kk < 32; ++kk) {
            float4 a4 = *(const float4*)&As[kk][ty * 4];
            float4 b4 = *(const float4*)&Bs[kk][tx * 4];
            acc[0][0]=fmaf(a4.x,b4.x,acc[0][0]); acc[0][1]=fmaf(a4.x,b4.y,acc[0][1]);
            acc[0][2]=fmaf(a4.x,b4.z,acc[0][2]); acc[0][3]=fmaf(a4.x,b4.w,acc[0][3]);
            acc[1][0]=fmaf(a4.y,b4.x,acc[1][0]); acc[1][1]=fmaf(a4.y,b4.y,acc[1][1]);
            acc[1][2]=fmaf(a4.y,b4.z,acc[1][2]); acc[1][3]=fmaf(a4.y,b4.w,acc[1][3]);
            acc[2][0]=fmaf(a4.z,b4.x,acc[2][0]); acc[2][1]=fmaf(a4.z,b4.y,acc[2][1]);
            acc[2][2]=fmaf(a4.z,b4.z,acc[2][2]); acc[2][3]=fmaf(a4.z,b4.w,acc[2][3]);
            acc[3][0]=fmaf(a4.w,b4.x,acc[3][0]); acc[3][1]=fmaf(a4.w,b4.y,acc[3][1]);
            acc[3][2]=fmaf(a4.w,b4.z,acc[3][2]); acc[3][3]=fmaf(a4.w,b4.w,acc[3][3]);
        }
        __syncthreads();
    }
    if (MODE == 0) {
        float4 bz = *(const float4*)&bias[n0 + tx * 4];
        #pragma unroll
        for (int i = 0; i < 4; ++i) {
            int m = m0 + ty * 4 + i;
            float4 o = { acc[i][0] + bz.x, acc[i][1] + bz.y, acc[i][2] + bz.z, acc[i][3] + bz.w };
            *(float4*)&Cout[(size_t)m * Nn + n0 + tx * 4] = o;
        }
    } else if (MODE == 1) {
        int b_ = m0 >> 8;
        int l0 = (m0 & 255) + ty * 4;
        f16x2* T4 = (f16x2*)Cout;
        #pragma unroll
        for (int j = 0; j < 4; ++j) {
            int h = n0 + tx * 4 + j;
            size_t base = (((size_t)(b_ * 64 + (h >> 2)) * 128) + (l0 >> 1)) * 4 + (h & 3);
            f16x2 v01 = { (_Float16)tanh_(acc[0][j]), (_Float16)tanh_(acc[1][j]) };
            f16x2 v23 = { (_Float16)tanh_(acc[2][j]), (_Float16)tanh_(acc[3][j]) };
            T4[base] = v01;       // pair (2*(l0>>1), +1) for h
            T4[base + 4] = v23;   // next l2
        }
    } else {
        int l0 = m0 + ty * 4;           // global row (b*256 + l)
        f16x2* P4 = (f16x2*)Cout;
        #pragma unroll
        for (int j = 0; j < 4; ++j) {
            int col = n0 + tx * 4 + j;
            size_t base = ((size_t)(l0 >> 3) * 768 + col) * 4 + ((l0 >> 1) & 3);
            f16x2 v01 = { (_Float16)acc[0][j], (_Float16)acc[1][j] };
            f16x2 v23 = { (_Float16)acc[2][j], (_Float16)acc[3][j] };
            P4[base] = v01;
            P4[base + 1] = v23;
        }
    }
}

// ---------- anchor GRU: one WG/batch, fp16 (reg slice + stream) — R5/R8-proven ----------
__global__ __launch_bounds__(768) void anchor_rnn(
    const float* __restrict__ GI, const int* __restrict__ lens,
    const float* __restrict__ bhh, const __half* __restrict__ WhaRH,
    const __half* __restrict__ WhaSH,
    float* __restrict__ AO, __half* __restrict__ AOH,
    float* __restrict__ hid, float* __restrict__ outp)
{
    __shared__ float gh[768];
    __shared__ __align__(16) float hs[256];
    __shared__ __align__(16) f16x2 hx2[128];
    __shared__ float bhhS[768];
    int bid = blockIdx.x, tid = threadIdx.x;
    int len = lens[bid];

    f16x2 wreg[64];
    {
        const float4* s = (const float4*)WhaRH + (size_t)tid * 16;
        #pragma unroll
        for (int u = 0; u < 16; ++u) {
            F4H8 c; c.f4 = s[u];
            wreg[4*u+0] = c.h2[0]; wreg[4*u+1] = c.h2[1];
            wreg[4*u+2] = c.h2[2]; wreg[4*u+3] = c.h2[3];
        }
    }
    if (tid < 256) hs[tid] = 0.f;
    if (tid < 128) { f16x2 z = {(_Float16)0.f, (_Float16)0.f}; hx2[tid] = z; }
    bhhS[tid] = bhh[tid];
    float sum = 0.f;
    __syncthreads();

    for (int t = 0; t < LAV; ++t) {
        { // gh[j] = W_hh_a[j,:] @ h (+ b_hh): k2 0..63 from regs + k2 64..127 streamed
            float a0=0.f,a1=0.f,a2=0.f,a3=0.f;
            const float4* xb = (const float4*)hx2;
            #pragma unroll
            for (int u = 0; u < 16; ++u) {
                F4H8 xv; xv.f4 = xb[u];
                a0 = __builtin_amdgcn_fdot2(wreg[4*u+0], xv.h2[0], a0, false);
                a1 = __builtin_amdgcn_fdot2(wreg[4*u+1], xv.h2[1], a1, false);
                a2 = __builtin_amdgcn_fdot2(wreg[4*u+2], xv.h2[2], a2, false);
                a3 = __builtin_amdgcn_fdot2(wreg[4*u+3], xv.h2[3], a3, false);
            }
            const uint2* wsp = (const uint2*)WhaSH + tid;
            float b0=0.f,b1=0.f;
            #pragma unroll
            for (int i2 = 0; i2 < 32; ++i2) {   // full 32 i2 slots (k2 64..127)
                U2H4 w; w.u2 = wsp[(size_t)i2 * 768];
                U2H4 xx; xx.u2 = *(const uint2*)&hx2[64 + 2 * i2];
                b0 = __builtin_amdgcn_fdot2(w.h2[0], xx.h2[0], b0, false);
                b1 = __builtin_amdgcn_fdot2(w.h2[1], xx.h2[1], b1, false);
            }
            gh[tid] = ((a0 + a1) + (a2 + a3)) + (b0 + b1) + bhhS[tid];
        }
        __syncthreads();
        if (tid < 256) {
            const float* gi = GI + ((size_t)t * BB + bid) * G3;
            float r = sigm(gi[tid] + gh[tid]);
            float z = sigm(gi[256 + tid] + gh[256 + tid]);
            float n = tanh_(fmaf(r, gh[512 + tid], gi[512 + tid]));
            float hk = hs[tid];
            float hn = (1.f - z) * n + z * hk;
            bool valid = (t < len);
            float hnew = valid ? hn : hk;
            hs[tid] = hnew;
            float ov = valid ? hn : 0.f;
            AO[((size_t)bid * LAV + t) * HV + tid] = ov;
            AOH[((size_t)bid * LAV + t) * HV + tid] = __float2half(ov);
            sum += ov;
            float other = __shfl_xor(hnew, 1, 64);
            if (!(tid & 1)) {
                f16x2 v = { (_Float16)hnew, (_Float16)other };
                hx2[tid >> 1] = v;
            }
        }
        __syncthreads();
    }
    if (tid < 256) {
        outp[bid * HV + tid] = sum / (float)len;
        hid[bid * HV + tid] = hs[tid];
    }
}

// ---------- candidate GRU + attention: one WG/batch; quad-k float4 loads throughout ----------
// A(q full+tanh | rzh full | nh full; GI prefetch) C(scores) D1(max) D2(exp+sum)
// E'(gateC = attn @ P) H(gate + h update)
__global__ __launch_bounds__(1024) void cand_rnn(
    const float* __restrict__ GI, const int* __restrict__ lens,
    const float* __restrict__ bhh, const __half* __restrict__ Wrz4,
    const __half* __restrict__ Wn4, const __half* __restrict__ Wq4,
    const float* __restrict__ v_att, const __half* __restrict__ P4H,
    const __half* __restrict__ T4H, const float* __restrict__ hid,
    float* __restrict__ outp)
{
    __shared__ __align__(16) f16x2 x2[128];        // h pairs (read as float4 quads)
    __shared__ __align__(16) float hs[256];
    __shared__ __align__(16) float2 tqv[256];      // {tq, v*tq}
    __shared__ float vls[256];
    __shared__ __align__(16) __half attnH[256];    // exp(s-mx) fp16 (read as float4 quads)
    __shared__ __align__(16) float redBig[2048];   // score partials (C)
    __shared__ __align__(16) float redRZh[512];    // A -> H (complete sums)
    __shared__ __align__(16) float redNh[256];     // A -> H (complete sums)
    __shared__ __align__(16) float gateC[768];     // E' -> H
    __shared__ float bhhS[768];
    __shared__ float wred[8];

    int tid = threadIdx.x;
    int b = blockIdx.x;
    int len = lens[b];

    const float4* Wq4f  = (const float4*)Wq4;
    const float4* Wrz4f = (const float4*)Wrz4;
    const float4* Wn4f  = (const float4*)Wn4;
    const float4* T4f   = (const float4*)T4H + (size_t)b * 64 * 128;
    const float4* P4f   = (const float4*)P4H + (size_t)b * 32 * 768;
    const float4* x4    = (const float4*)x2;
    const float4* at4   = (const float4*)attnH;

    if (tid < 256) { hs[tid] = hid[b * HV + tid]; vls[tid] = v_att[tid]; }
    if (tid < 768) bhhS[tid] = bhh[tid];
    __syncthreads();
    if (tid < 128) {
        f16x2 v = { (_Float16)hs[2 * tid], (_Float16)hs[2 * tid + 1] };
        x2[tid] = v;
    }
    __syncthreads();

    float csum = 0.f;

    for (int t = 0; t < LCV; ++t) {
        float gir = 0.f, giz = 0.f, gin = 0.f;
        // ---- A: full-output role split; 32 float4 loads + 128 fdot2 per thread ----
        if (tid < 256) {
            const float* gi = GI + ((size_t)t * BB + b) * G3 + tid;
            gir = gi[0]; giz = gi[256]; gin = gi[512];
            int m = tid;
            float a0 = 0.f, a1 = 0.f, a2 = 0.f, a3 = 0.f;
            #pragma unroll 8
            for (int kq = 0; kq < 32; ++kq) {
                F4H8 w; w.f4 = Wq4f[(size_t)kq * 256 + m];
                F4H8 xx; xx.f4 = x4[kq];
                a0 = __builtin_amdgcn_fdot2(w.h2[0], xx.h2[0], a0, false);
                a1 = __builtin_amdgcn_fdot2(w.h2[1], xx.h2[1], a1, false);
                a2 = __builtin_amdgcn_fdot2(w.h2[2], xx.h2[2], a2, false);
                a3 = __builtin_amdgcn_fdot2(w.h2[3], xx.h2[3], a3, false);
            }
            float tq = tanh_((a0 + a1) + (a2 + a3));
            tqv[m] = make_float2(tq, vls[m] * tq);
        } else if (tid < 768) {
            int j = tid - 256;
            float a0 = 0.f, a1 = 0.f, a2 = 0.f, a3 = 0.f;
            #pragma unroll 8
            for (int kq = 0; kq < 32; ++kq) {
                F4H8 w; w.f4 = Wrz4f[(size_t)kq * 512 + j];
                F4H8 xx; xx.f4 = x4[kq];
                a0 = __builtin_amdgcn_fdot2(w.h2[0], xx.h2[0], a0, false);
                a1 = __builtin_amdgcn_fdot2(w.h2[1], xx.h2[1], a1, false);
                a2 = __builtin_amdgcn_fdot2(w.h2[2], xx.h2[2], a2, false);
                a3 = __builtin_amdgcn_fdot2(w.h2[3], xx.h2[3], a3, false);
            }
            redRZh[j] = (a0 + a1) + (a2 + a3);
        } else {
            int j = tid - 768;
            float a0 = 0.f, a1 = 0.f, a2 = 0.f, a3 = 0.f;
            #pragma unroll 8
            for (int kq = 0; kq < 32; ++kq) {
                F4H8 w; w.f4 = Wn4f[(size_t)kq * 256 + j];
                F4H8 xx; xx.f4 = x4[kq];
                a0 = __builtin_amdgcn_fdot2(w.h2[0], xx.h2[0], a0, false);
                a1 = __builtin_amdgcn_fdot2(w.h2[1], xx.h2[1], a1, false);
                a2 = __builtin_amdgcn_fdot2(w.h2[2], xx.h2[2], a2, false);
                a3 = __builtin_amdgcn_fdot2(w.h2[3], xx.h2[3], a3, false);
            }
            redNh[j] = (a0 + a1) + (a2 + a3);
        }
        __syncthreads();
        { // C: scores; 8 float4 loads, 32 h per thread
            int l2 = tid & 127, hg = tid >> 7;
            const float4* Tb = T4f + (size_t)(hg * 8) * 128 + l2;
            float s0 = 0.f, s1 = 0.f;
            #pragma unroll
            for (int i = 0; i < 8; ++i) {
                F4H8 tv4; tv4.f4 = Tb[(size_t)i * 128];
                #pragma unroll
                for (int c = 0; c < 4; ++c) {
                    int h = (hg * 8 + i) * 4 + c;
                    float2 tv = tqv[h];
                    float vv = vls[h];
                    float T0 = (float)tv4.h2[c].x, T1 = (float)tv4.h2[c].y;
                    float d0 = fmaxf(fmaf(T0, tv.x, 1.f), 1e-6f);
                    float d1 = fmaxf(fmaf(T1, tv.x, 1.f), 1e-6f);
                    s0 = fmaf(fmaf(vv, T0, tv.y), rcp_(d0), s0);
                    s1 = fmaf(fmaf(vv, T1, tv.y), rcp_(d1), s1);
                }
            }
            redBig[hg * 256 + 2 * l2] = s0;
            redBig[hg * 256 + 2 * l2 + 1] = s1;
        }
        __syncthreads();
        float sv = 0.f;
        if (tid < 256) { // D1: reduce score partials + wave max
            #pragma unroll
            for (int hg = 0; hg < 8; ++hg) sv += redBig[hg * 256 + tid];
            float m = sv;
            #pragma unroll
            for (int o = 1; o < 64; o <<= 1) m = fmaxf(m, __shfl_xor(m, o, 64));
            if ((tid & 63) == 0) wred[tid >> 6] = m;
        }
        __syncthreads();
        if (tid < 256) { // D2: exp(s - max) in fp16 + wave sum
            float mx = fmaxf(fmaxf(wred[0], wred[1]), fmaxf(wred[2], wred[3]));
            float e = __expf(sv - mx);
            attnH[tid] = __float2half(e);
            float s = e;
            #pragma unroll
            for (int o = 1; o < 64; o <<= 1) s += __shfl_xor(s, o, 64);
            if ((tid & 63) == 0) wred[4 + (tid >> 6)] = s;
        }
        __syncthreads();
        if (tid < 768) { // E': gateC[j] = sum_l attn[l] * P[l][j]; 32 float4 loads
            float a0 = 0.f, a1 = 0.f;
            #pragma unroll 8
            for (int lq = 0; lq < 32; ++lq) {
                F4H8 p; p.f4 = P4f[(size_t)lq * 768 + tid];
                F4H8 aa; aa.f4 = at4[lq];
                a0 = __builtin_amdgcn_fdot2(p.h2[0], aa.h2[0], a0, false);
                a1 = __builtin_amdgcn_fdot2(p.h2[1], aa.h2[1], a1, false);
                a0 = __builtin_amdgcn_fdot2(p.h2[2], aa.h2[2], a0, false);
                a1 = __builtin_amdgcn_fdot2(p.h2[3], aa.h2[3], a1, false);
            }
            gateC[tid] = a0 + a1;
        }
        __syncthreads();
        if (tid < 256) { // H: gate + GRU update (complete sums, prefetched gi)
            float rs = rcp_(wred[4] + wred[5] + wred[6] + wred[7]);
            float rr = redRZh[tid] + gateC[tid] * rs;
            float zz = redRZh[256 + tid] + gateC[256 + tid] * rs;
            float nh = redNh[tid];
            float nc = gateC[512 + tid] * rs;
            float r = sigm(gir + rr + bhhS[tid]);
            float z = sigm(giz + zz + bhhS[256 + tid]);
            float n = tanh_(gin + nc + r * (nh + bhhS[512 + tid]));
            float hk = hs[tid];
            float hn = (1.f - z) * n + z * hk;
            float hnew = (len < t) ? hk : hn;        // strict '<' per reference
            hs[tid] = hnew;
            if (t < len) csum += hnew;
            float other = __shfl_xor(hnew, 1, 64);
            if ((tid & 1) == 0) {
                f16x2 v = { (_Float16)hnew, (_Float16)other };
                x2[tid >> 1] = v;
            }
        }
        __syncthreads();
    }
    if (tid < 256) outp[8192 + b * HV + tid] = csum / (float)len;
}

extern "C" void kernel_launch(void* const* d_in, const int* in_sizes, int n_in,
                              void* d_out, int out_size, void* d_ws, size_t ws_size,
                              hipStream_t stream) {
    const int* anchor_input     = (const int*)d_in[0];
    const int* anchor_length    = (const int*)d_in[1];
    const int* candidate_input  = (const int*)d_in[2];
    const int* candidate_length = (const int*)d_in[3];
    const float* emb    = (const float*)d_in[5];
    const float* W_ih_a = (const float*)d_in[6];
    const float* W_hh_a = (const float*)d_in[7];
    const float* b_ih_a = (const float*)d_in[8];
    const float* b_hh_a = (const float*)d_in[9];
    const float* W_ih_c = (const float*)d_in[10];
    const float* W_hh_c = (const float*)d_in[11];
    const float* b_ih_c = (const float*)d_in[12];
    const float* b_hh_c = (const float*)d_in[13];
    const float* Wq     = (const float*)d_in[14];
    const float* Wk     = (const float*)d_in[15];
    const float* v_att  = (const float*)d_in[16];
    float* out = (float*)d_out;

    // workspace layout (float units), ~71.3 MB
    float* ws = (float*)d_ws;
    size_t off = 0;
    float* GI_a  = ws + off; off += (size_t)LAV * BB * G3;     // 6291456 (dead after anchor)
    float* GI_c  = ws + off; off += (size_t)LCV * BB * G3;     // 6291456
    float* AO    = ws + off; off += (size_t)BB * LAV * HV;     // 2097152
    float* hid   = ws + off; off += (size_t)BB * HV;           // 8192
    float* WT_a  = ws + off; off += 300 * 768;                 // 230400
    float* WT_cx = ws + off; off += 300 * 768;                 // 230400
    __half* T4H   = (__half*)(ws + off); off += (size_t)BB * HV * LAV / 2;  // quad pack
    __half* AOH   = (__half*)(ws + off); off += (size_t)BB * LAV * HV / 2;  // [b][l][h] pairs
    __half* WhaRH = (__half*)(ws + off); off += 98304 / 2;
    __half* WhaSH = (__half*)(ws + off); off += 98304 / 2;
    __half* Wq4   = (__half*)(ws + off); off += 65536 / 2;
    __half* Wrz4  = (__half*)(ws + off); off += 131072 / 2;
    __half* Wn4   = (__half*)(ws + off); off += 65536 / 2;
    float* WcxCT  = ws + off; off += 256 * 768;                // 196608
    // P4 [1024 lq][768][4 c] half = 12.6 MB, aliased onto GI_a (dead once anchor finishes)
    __half* P4H = (__half*)GI_a;

    prep_pack<<<dim3(900, 8), 256, 0, stream>>>(W_ih_a, W_ih_c, W_hh_a, W_hh_c, Wq,
                                                WT_a, WT_cx, WhaRH, WhaSH, Wq4, Wrz4, Wn4, WcxCT);
    gemm_tile<0><<<dim3(128, 12), 256, 0, stream>>>(emb, anchor_input, DV, WT_a, DV, G3, b_ih_a, GI_a);
    gemm_tile<0><<<dim3(128, 12), 256, 0, stream>>>(emb, candidate_input, DV, WT_cx, DV, G3, b_ih_c, GI_c);
    anchor_rnn<<<32, 768, 0, stream>>>(GI_a, anchor_length, b_hh_a, WhaRH, WhaSH, AO, AOH, hid, out);
    gemm_tile<1><<<dim3(128, 4), 256, 0, stream>>>(AO, nullptr, HV, Wk, HV, HV, nullptr, (float*)T4H);
    // P = AO @ W_ih_c[:,300:]^T  -> quad pack (writes over dead GI_a)
    gemm_tile<2><<<dim3(128, 12), 256, 0, stream>>>(AO, nullptr, HV, WcxCT, HV, G3, nullptr, (float*)P4H);
    cand_rnn<<<32, 1024, 0, stream>>>(GI_c, candidate_length, b_hh_c, Wrz4, Wn4, Wq4,
                                      v_att, P4H, T4H, hid, out);
}